// Round 2
// baseline (78.039 us; speedup 1.0000x reference)
//
#include <hip/hip_runtime.h>

// RSA layer, last-row-only, 2-D tiled (j x u) formulation, SINGLE kernel:
// the old rsa_part (proven 62.5 us config) + last-block fin reduction.
//
// out[u] = (sum_j e^{s[j,u]} * fs[j,u]) / (sum_j e^{s[j,u]})
//   s[j,u] = sum_k fs[j,k] * v[k,u],   v[k,u] = w_hi[k,u] + w_dot[u]*input[k]
// (proj_hj[1023,:] and b are constant in j -> cancel in the softmax over j;
//  |s| <~ 8 so e^s is fp32-safe without max subtraction -> partials over j
//  are linearly mergeable across blocks.)
// fs[j,k] = state[k, j+1] for j<1023;  fs[1023,k] = input[k].
//
// Grid: 256 blocks = 64 j-tiles (16 j each) x 4 u-quarters (32 u each).
// Block (jt,uq) reads ONLY: w_hi[:, 32uq:32uq+32] (16 KB), state cols
// [16jt,16jt+16) (8 KB), input, w_dot quarter -> ~7 float4 loads per thread,
// all independent, ONE cold-latency round. Column c maps to j=c-1; block 0's
// dead c=0 slot is patched with j=1023 (fs=input). Partial num/den per u go
// to ws; the LAST block to finish (device-global ticket) re-reads the 64 KB
// of partials after an acquire fence and divides -- replaces the rsa_fin
// dispatch + inter-kernel gap. Reduction order identical to rsa_fin ->
// bit-identical output. Ticket resets to 0 before kernel exit, so every
// graph iteration starts from a clean counter (zero-init at module load).

constexpr int U    = 128;
constexpr int W    = 1024;
constexpr int JT   = 16;    // j's per block
constexpr int SSTR = 132;   // sliceT row stride floats; 132%32==4, 16B-aligned

__device__ unsigned g_ticket = 0;

__global__ __launch_bounds__(256) void rsa_part(
    const float* __restrict__ input,   // (128,)
    const float* __restrict__ state,   // (128,1024) row-major
    const float* __restrict__ w,       // (257,128) row-major
    float* __restrict__ ws,            // (4,64,64): [uq][jt][num32|den32]
    float* __restrict__ out)           // (128,)
{
    const int bid = blockIdx.x;
    const int jt  = bid >> 2;          // 0..63
    const int uq  = bid & 3;           // 0..3
    const int t   = threadIdx.x;
    const int uu  = t & 7;             // float4 u-group within the 32-u slice
    const int j   = (t >> 3) & 15;     // j_local
    const int kh  = t >> 7;            // k-half

    __shared__ __align__(16) float sliceT[JT][SSTR]; // fs[j_local][k]
    __shared__ __align__(16) float vv[U][32];        // v[k][u_local]
    __shared__ __align__(16) float sin_[U];
    __shared__ __align__(16) float mrg[JT][8][4];    // kh=1 partial acc
    __shared__ __align__(16) float red2[2][8][8];    // per-wave j-reduced {num4,den4}
    __shared__ float sden[U];                        // fin: denominators
    __shared__ unsigned amLast;                      // fin: ticket result

    // ---- issue ALL global loads up front (one vmcnt round) ----
    float4 in4;
    if (t < 32) in4 = ((const float4*)input)[t];
    const float4 wdq = ((const float4*)(w + 2 * U * U + uq * 32))[uu];
    float4 wh[4];
    #pragma unroll
    for (int i = 0; i < 4; ++i) {
        const int k = (t >> 3) + 32 * i;
        wh[i] = ((const float4*)w)[k * 32 + uq * 8 + uu];     // w_hi[k, u-slice]
    }
    float4 st[2];
    #pragma unroll
    for (int i = 0; i < 2; ++i) {
        const int p = t + 256 * i;                            // 0..511
        const int k = p >> 2;
        const int j4 = p & 3;
        st[i] = ((const float4*)state)[k * 256 + jt * 4 + j4]; // cols 16jt+4j4..+3
    }

    if (t < 32) ((float4*)sin_)[t] = in4;
    __syncthreads();                                          // sin_ ready

    // ---- build vv[k][u] = w_hi + w_dot*input[k]; stage sliceT (transpose) ----
    #pragma unroll
    for (int i = 0; i < 4; ++i) {
        const int k = (t >> 3) + 32 * i;
        const float ik = sin_[k];
        float4 r;
        r.x = fmaf(wdq.x, ik, wh[i].x);
        r.y = fmaf(wdq.y, ik, wh[i].y);
        r.z = fmaf(wdq.z, ik, wh[i].z);
        r.w = fmaf(wdq.w, ik, wh[i].w);
        *(float4*)&vv[k][4 * uu] = r;
    }
    #pragma unroll
    for (int i = 0; i < 2; ++i) {
        const int p = t + 256 * i;
        const int k = p >> 2;
        const int j4 = p & 3;
        sliceT[4 * j4 + 0][k] = st[i].x;
        sliceT[4 * j4 + 1][k] = st[i].y;
        sliceT[4 * j4 + 2][k] = st[i].z;
        sliceT[4 * j4 + 3][k] = st[i].w;
    }
    __syncthreads();                                          // staged
    if (jt == 0 && t < U) sliceT[0][t] = sin_[t];             // c=0 -> j=1023
    __syncthreads();

    // ---- GEMM: acc[m] = partial_k s[j, uq*32+4uu+m] over k-half ----
    const int kb0 = kh * 64;
    const float* aR = &sliceT[j][kb0];
    float4 acc = {0.f, 0.f, 0.f, 0.f};
    #pragma unroll
    for (int kc = 0; kc < 16; ++kc) {
        const float4 a4 = *(const float4*)(aR + 4 * kc);
        const float4 v0 = *(const float4*)&vv[kb0 + 4 * kc + 0][4 * uu];
        const float4 v1 = *(const float4*)&vv[kb0 + 4 * kc + 1][4 * uu];
        const float4 v2 = *(const float4*)&vv[kb0 + 4 * kc + 2][4 * uu];
        const float4 v3 = *(const float4*)&vv[kb0 + 4 * kc + 3][4 * uu];
        acc.x = fmaf(a4.x, v0.x, acc.x); acc.y = fmaf(a4.x, v0.y, acc.y);
        acc.z = fmaf(a4.x, v0.z, acc.z); acc.w = fmaf(a4.x, v0.w, acc.w);
        acc.x = fmaf(a4.y, v1.x, acc.x); acc.y = fmaf(a4.y, v1.y, acc.y);
        acc.z = fmaf(a4.y, v1.z, acc.z); acc.w = fmaf(a4.y, v1.w, acc.w);
        acc.x = fmaf(a4.z, v2.x, acc.x); acc.y = fmaf(a4.z, v2.y, acc.y);
        acc.z = fmaf(a4.z, v2.z, acc.z); acc.w = fmaf(a4.z, v2.w, acc.w);
        acc.x = fmaf(a4.w, v3.x, acc.x); acc.y = fmaf(a4.w, v3.y, acc.y);
        acc.z = fmaf(a4.w, v3.z, acc.z); acc.w = fmaf(a4.w, v3.w, acc.w);
    }

    // ---- merge k-halves ----
    if (kh) *(float4*)&mrg[j][uu][0] = acc;
    __syncthreads();
    if (!kh) {
        const float4 o = *(const float4*)&mrg[j][uu][0];
        acc.x += o.x; acc.y += o.y; acc.z += o.z; acc.w += o.w;

        // softmax partials for this (j, u0..u0+3)
        const float4 fs4 = *(const float4*)&sliceT[j][uq * 32 + 4 * uu];
        float4 e, n;
        e.x = __expf(acc.x); e.y = __expf(acc.y);
        e.z = __expf(acc.z); e.w = __expf(acc.w);
        n.x = fs4.x * e.x;   n.y = fs4.y * e.y;
        n.z = fs4.z * e.z;   n.w = fs4.w * e.w;

        // reduce over the wave's 8 j's (lanes strided by 8 share uu)
        #pragma unroll
        for (int o8 = 8; o8 < 64; o8 <<= 1) {
            n.x += __shfl_down(n.x, o8, 64); n.y += __shfl_down(n.y, o8, 64);
            n.z += __shfl_down(n.z, o8, 64); n.w += __shfl_down(n.w, o8, 64);
            e.x += __shfl_down(e.x, o8, 64); e.y += __shfl_down(e.y, o8, 64);
            e.z += __shfl_down(e.z, o8, 64); e.w += __shfl_down(e.w, o8, 64);
        }
        const int lane = t & 63, wv = t >> 6;                 // wv in {0,1}
        if (lane < 8) {
            red2[wv][lane][0] = n.x; red2[wv][lane][1] = n.y;
            red2[wv][lane][2] = n.z; red2[wv][lane][3] = n.w;
            red2[wv][lane][4] = e.x; red2[wv][lane][5] = e.y;
            red2[wv][lane][6] = e.z; red2[wv][lane][7] = e.w;
        }
    }
    __syncthreads();

    if (t < 32) {
        const int ug = t >> 2, m = t & 3;
        const float num = red2[0][ug][m]     + red2[1][ug][m];
        const float den = red2[0][ug][4 + m] + red2[1][ug][4 + m];
        const int base = (uq * 64 + jt) * 64;
        ws[base + t]      = num;
        ws[base + 32 + t] = den;
    }

    // ---- last-block fin: replaces the rsa_fin dispatch ----
    __threadfence();                       // release: partials device-visible
    if (t == 0)
        amLast = (atomicAdd(&g_ticket, 1u) == 255u) ? 1u : 0u;
    __syncthreads();
    if (amLast) {                          // block-uniform branch
        __threadfence();                   // acquire: drop stale cached lines
        const int u  = t & (U - 1);
        const int nd = t >> 7;             // 0: num, 1: den
        const float* base2 = ws + (size_t)(u >> 5) * 64 * 64 + nd * 32 + (u & 31);
        float s = 0.0f;
        #pragma unroll 16
        for (int jt2 = 0; jt2 < 64; ++jt2) s += base2[jt2 * 64];
        if (nd) sden[u] = s;
        __syncthreads();
        if (!nd) out[u] = s / sden[u];
        if (t == 0) atomicExch(&g_ticket, 0u);  // clean for next iteration
    }
}

extern "C" void kernel_launch(void* const* d_in, const int* in_sizes, int n_in,
                              void* d_out, int out_size, void* d_ws, size_t ws_size,
                              hipStream_t stream) {
    const float* input = (const float*)d_in[0];   // (1,128)
    const float* state = (const float*)d_in[1];   // (128,1024)
    const float* w     = (const float*)d_in[2];   // (257,128)
    // d_in[3] = b (zeros; cancels in softmax) -- unused
    float* out = (float*)d_out;                   // (1,128)
    float* ws  = (float*)d_ws;                    // 64 KB partials

    rsa_part<<<dim3(256), dim3(256), 0, stream>>>(input, state, w, ws, out);
}

// Round 3
// 62.633 us; speedup vs baseline: 1.2460x; 1.2460x over previous
//
#include <hip/hip_runtime.h>

// RSA layer, last-row-only, 2-D tiled (j x u) formulation.
//
// out[u] = (sum_j e^{s[j,u]} * fs[j,u]) / (sum_j e^{s[j,u]})
//   s[j,u] = sum_k fs[j,k] * v[k,u],   v[k,u] = w_hi[k,u] + w_dot[u]*input[k]
// (proj_hj[1023,:] and b are constant in j -> cancel in the softmax over j;
//  |s| <~ 8 so e^s is fp32-safe without max subtraction -> partials over j
//  are linearly mergeable across blocks.)
// fs[j,k] = state[k, j+1] for j<1023;  fs[1023,k] = input[k].
//
// Grid: 256 blocks = 64 j-tiles (16 j each) x 4 u-quarters (32 u each).
// Block (jt,uq) reads ONLY: w_hi[:, 32uq:32uq+32] (16 KB), state cols
// [16jt,16jt+16) (8 KB), input, w_dot quarter -> ~7 float4 loads per thread,
// all independent, ONE cold-latency round. Column c maps to j=c-1; block 0's
// dead c=0 slot is patched with j=1023 (fs=input). Partial num/den per u go
// to ws; a tiny second kernel reduces 64 j-tiles and divides.
//
// Session notes (measured):
//   R0 this exact kernel:                62.5 us  <- best
//   R1 fused u-split (no ws):            64.9 us  (redundant state streams)
//   R2 last-block fin + threadfence:     78.0 us  (device-fence + cross-XCD
//                                                  L2 writeback cost ~15 us)
// Two-dispatch j-split is the proven optimum on this non-coherent-L2 chip.

constexpr int U    = 128;
constexpr int W    = 1024;
constexpr int JT   = 16;    // j's per block
constexpr int SSTR = 132;   // sliceT row stride floats; 132%32==4, 16B-aligned

__global__ __launch_bounds__(256) void rsa_part(
    const float* __restrict__ input,   // (128,)
    const float* __restrict__ state,   // (128,1024) row-major
    const float* __restrict__ w,       // (257,128) row-major
    float* __restrict__ ws)            // (4,64,64): [uq][jt][num32|den32]
{
    const int bid = blockIdx.x;
    const int jt  = bid >> 2;          // 0..63
    const int uq  = bid & 3;           // 0..3
    const int t   = threadIdx.x;
    const int uu  = t & 7;             // float4 u-group within the 32-u slice
    const int j   = (t >> 3) & 15;     // j_local
    const int kh  = t >> 7;            // k-half

    __shared__ __align__(16) float sliceT[JT][SSTR]; // fs[j_local][k]
    __shared__ __align__(16) float vv[U][32];        // v[k][u_local]
    __shared__ __align__(16) float sin_[U];
    __shared__ __align__(16) float mrg[JT][8][4];    // kh=1 partial acc
    __shared__ __align__(16) float red2[2][8][8];    // per-wave j-reduced {num4,den4}

    // ---- issue ALL global loads up front (one vmcnt round) ----
    float4 in4;
    if (t < 32) in4 = ((const float4*)input)[t];
    const float4 wdq = ((const float4*)(w + 2 * U * U + uq * 32))[uu];
    float4 wh[4];
    #pragma unroll
    for (int i = 0; i < 4; ++i) {
        const int k = (t >> 3) + 32 * i;
        wh[i] = ((const float4*)w)[k * 32 + uq * 8 + uu];     // w_hi[k, u-slice]
    }
    float4 st[2];
    #pragma unroll
    for (int i = 0; i < 2; ++i) {
        const int p = t + 256 * i;                            // 0..511
        const int k = p >> 2;
        const int j4 = p & 3;
        st[i] = ((const float4*)state)[k * 256 + jt * 4 + j4]; // cols 16jt+4j4..+3
    }

    if (t < 32) ((float4*)sin_)[t] = in4;
    __syncthreads();                                          // sin_ ready

    // ---- build vv[k][u] = w_hi + w_dot*input[k]; stage sliceT (transpose) ----
    #pragma unroll
    for (int i = 0; i < 4; ++i) {
        const int k = (t >> 3) + 32 * i;
        const float ik = sin_[k];
        float4 r;
        r.x = fmaf(wdq.x, ik, wh[i].x);
        r.y = fmaf(wdq.y, ik, wh[i].y);
        r.z = fmaf(wdq.z, ik, wh[i].z);
        r.w = fmaf(wdq.w, ik, wh[i].w);
        *(float4*)&vv[k][4 * uu] = r;
    }
    #pragma unroll
    for (int i = 0; i < 2; ++i) {
        const int p = t + 256 * i;
        const int k = p >> 2;
        const int j4 = p & 3;
        sliceT[4 * j4 + 0][k] = st[i].x;
        sliceT[4 * j4 + 1][k] = st[i].y;
        sliceT[4 * j4 + 2][k] = st[i].z;
        sliceT[4 * j4 + 3][k] = st[i].w;
    }
    __syncthreads();                                          // staged
    if (jt == 0 && t < U) sliceT[0][t] = sin_[t];             // c=0 -> j=1023
    __syncthreads();

    // ---- GEMM: acc[m] = partial_k s[j, uq*32+4uu+m] over k-half ----
    const int kb0 = kh * 64;
    const float* aR = &sliceT[j][kb0];
    float4 acc = {0.f, 0.f, 0.f, 0.f};
    #pragma unroll
    for (int kc = 0; kc < 16; ++kc) {
        const float4 a4 = *(const float4*)(aR + 4 * kc);
        const float4 v0 = *(const float4*)&vv[kb0 + 4 * kc + 0][4 * uu];
        const float4 v1 = *(const float4*)&vv[kb0 + 4 * kc + 1][4 * uu];
        const float4 v2 = *(const float4*)&vv[kb0 + 4 * kc + 2][4 * uu];
        const float4 v3 = *(const float4*)&vv[kb0 + 4 * kc + 3][4 * uu];
        acc.x = fmaf(a4.x, v0.x, acc.x); acc.y = fmaf(a4.x, v0.y, acc.y);
        acc.z = fmaf(a4.x, v0.z, acc.z); acc.w = fmaf(a4.x, v0.w, acc.w);
        acc.x = fmaf(a4.y, v1.x, acc.x); acc.y = fmaf(a4.y, v1.y, acc.y);
        acc.z = fmaf(a4.y, v1.z, acc.z); acc.w = fmaf(a4.y, v1.w, acc.w);
        acc.x = fmaf(a4.z, v2.x, acc.x); acc.y = fmaf(a4.z, v2.y, acc.y);
        acc.z = fmaf(a4.z, v2.z, acc.z); acc.w = fmaf(a4.z, v2.w, acc.w);
        acc.x = fmaf(a4.w, v3.x, acc.x); acc.y = fmaf(a4.w, v3.y, acc.y);
        acc.z = fmaf(a4.w, v3.z, acc.z); acc.w = fmaf(a4.w, v3.w, acc.w);
    }

    // ---- merge k-halves ----
    if (kh) *(float4*)&mrg[j][uu][0] = acc;
    __syncthreads();
    if (!kh) {
        const float4 o = *(const float4*)&mrg[j][uu][0];
        acc.x += o.x; acc.y += o.y; acc.z += o.z; acc.w += o.w;

        // softmax partials for this (j, u0..u0+3)
        const float4 fs4 = *(const float4*)&sliceT[j][uq * 32 + 4 * uu];
        float4 e, n;
        e.x = __expf(acc.x); e.y = __expf(acc.y);
        e.z = __expf(acc.z); e.w = __expf(acc.w);
        n.x = fs4.x * e.x;   n.y = fs4.y * e.y;
        n.z = fs4.z * e.z;   n.w = fs4.w * e.w;

        // reduce over the wave's 8 j's (lanes strided by 8 share uu)
        #pragma unroll
        for (int o8 = 8; o8 < 64; o8 <<= 1) {
            n.x += __shfl_down(n.x, o8, 64); n.y += __shfl_down(n.y, o8, 64);
            n.z += __shfl_down(n.z, o8, 64); n.w += __shfl_down(n.w, o8, 64);
            e.x += __shfl_down(e.x, o8, 64); e.y += __shfl_down(e.y, o8, 64);
            e.z += __shfl_down(e.z, o8, 64); e.w += __shfl_down(e.w, o8, 64);
        }
        const int lane = t & 63, wv = t >> 6;                 // wv in {0,1}
        if (lane < 8) {
            red2[wv][lane][0] = n.x; red2[wv][lane][1] = n.y;
            red2[wv][lane][2] = n.z; red2[wv][lane][3] = n.w;
            red2[wv][lane][4] = e.x; red2[wv][lane][5] = e.y;
            red2[wv][lane][6] = e.z; red2[wv][lane][7] = e.w;
        }
    }
    __syncthreads();

    if (t < 32) {
        const int ug = t >> 2, m = t & 3;
        const float num = red2[0][ug][m]     + red2[1][ug][m];
        const float den = red2[0][ug][4 + m] + red2[1][ug][4 + m];
        const int base = (uq * 64 + jt) * 64;
        ws[base + t]      = num;
        ws[base + 32 + t] = den;
    }
}

__global__ __launch_bounds__(256) void rsa_fin(
    const float* __restrict__ ws, float* __restrict__ out)
{
    __shared__ float sden[U];
    const int t  = threadIdx.x;
    const int u  = t & (U - 1);
    const int nd = t >> 7;                     // 0: num, 1: den
    const float* base = ws + (size_t)(u >> 5) * 64 * 64 + nd * 32 + (u & 31);
    float s = 0.0f;
    #pragma unroll 16
    for (int jt = 0; jt < 64; ++jt) s += base[jt * 64];
    if (nd) sden[u] = s;
    __syncthreads();
    if (!nd) out[u] = s / sden[u];
}

extern "C" void kernel_launch(void* const* d_in, const int* in_sizes, int n_in,
                              void* d_out, int out_size, void* d_ws, size_t ws_size,
                              hipStream_t stream) {
    const float* input = (const float*)d_in[0];   // (1,128)
    const float* state = (const float*)d_in[1];   // (128,1024)
    const float* w     = (const float*)d_in[2];   // (257,128)
    // d_in[3] = b (zeros; cancels in softmax) -- unused
    float* out = (float*)d_out;                   // (1,128)
    float* ws  = (float*)d_ws;                    // 64 KB partials

    rsa_part<<<dim3(256), dim3(256), 0, stream>>>(input, state, w, ws);
    rsa_fin<<<dim3(1), dim3(256), 0, stream>>>(ws, out);
}